// Round 6
// baseline (941.714 us; speedup 1.0000x reference)
//
#include <hip/hip_runtime.h>
#include <math.h>

// LowRankChristoffel: out = clip((((v@U)^2) @ W^T) * (1+sigmoid(x@Vw^T)), +-5)
// B=4, S=4096, D=2048, R=16, fp32.
//
// R6: R4 (84.5us) was capped at 16 waves/CU by its 137 KiB LDS; R5 proved
// moving U to L2 is worse (latency-bound, occupancy did NOT rise with big
// blocks). So: keep U in LDS but stage it in 32 KiB QUARTERS ([16][512]),
// loop stage->sync->accumulate->sync x4 with pp[] live in registers.
// 512-thread WGs, ~33 KiB LDS -> 4 WGs/CU = 32 waves/CU (standard path,
// no big-block co-residency bet). VGPR pinned <=64 via waves_per_eu(8);
// R4's counters (WRITE==output exactly) proved this body fits 64 w/o spill.

constexpr int D_DIM   = 2048;
constexpr int R_DIM   = 16;
constexpr int ROWS    = 16;      // rows per block
constexpr int THREADS = 512;     // 8 waves
constexpr int WAVES   = THREADS / 64;
constexpr int RB      = 2;       // rows per wave
constexpr int QD      = 512;     // d-columns per staged quarter
constexpr int NQ      = D_DIM / QD;   // 4 quarters

typedef float f32x2 __attribute__((ext_vector_type(2)));

__device__ __forceinline__ float clamp5(float v) {
    return fminf(fmaxf(v, -5.0f), 5.0f);
}
__device__ __forceinline__ float dot4(float4 a, float4 b) {
    return a.x * b.x + a.y * b.y + a.z * b.z + a.w * b.w;
}

extern "C" __global__ void __launch_bounds__(THREADS)
__attribute__((amdgpu_waves_per_eu(8)))
lrc_kernel(const float* __restrict__ v, const float* __restrict__ x,
           const float* __restrict__ U, const float* __restrict__ W,
           const float* __restrict__ Vw, float* __restrict__ out, int nrows)
{
    __shared__ float u_lds[R_DIM * QD];      // 32 KiB, one quarter of U^T
    __shared__ float sq_lds[ROWS * R_DIM];   // 1 KiB
    __shared__ float fac_lds[ROWS];

    const int tid  = threadIdx.x;
    const int lane = tid & 63;
    const int wave = tid >> 6;          // 0..7
    const int row0 = blockIdx.x * ROWS;

    // ---- phase 1: quarter-staged U^T; pp accumulators live across quarters ----
    {
        const int rl0 = wave * RB;
        const float* vb = v + (size_t)(row0 + rl0) * D_DIM;
        const float* xb = x + (size_t)(row0 + rl0) * D_DIM;

        float pp[RB][R_DIM];
        float xv[RB];
        #pragma unroll
        for (int k = 0; k < RB; ++k) {
            xv[k] = 0.0f;
            #pragma unroll
            for (int r = 0; r < R_DIM; ++r) pp[k][r] = 0.0f;
        }

        for (int q = 0; q < NQ; ++q) {
            // stage quarter q transposed: thread owns d = q*QD + tid
            {
                const int d = q * QD + tid;
                const float4* p = reinterpret_cast<const float4*>(U + (size_t)d * R_DIM);
                float u[R_DIM];
                #pragma unroll
                for (int c = 0; c < 4; ++c)
                    *reinterpret_cast<float4*>(&u[c * 4]) = p[c];
                #pragma unroll
                for (int r = 0; r < R_DIM; ++r)
                    u_lds[r * QD + tid] = u[r];   // stride-1 across threads: conflict-free
            }
            __syncthreads();

            #pragma unroll
            for (int i = 0; i < QD / 256; ++i) {       // 2 iters per quarter
                const int dl = i * 256 + lane * 4;     // local d in quarter
                const int dg = q * QD + dl;            // global d
                float4 v4[RB], x4[RB];
                #pragma unroll
                for (int k = 0; k < RB; ++k) {
                    v4[k] = *reinterpret_cast<const float4*>(vb + (size_t)k * D_DIM + dg);
                    x4[k] = *reinterpret_cast<const float4*>(xb + (size_t)k * D_DIM + dg);
                }
                const float4 vw4 = *reinterpret_cast<const float4*>(Vw + dg);  // L1/L2 hit
                #pragma unroll
                for (int k = 0; k < RB; ++k) xv[k] += dot4(x4[k], vw4);
                #pragma unroll
                for (int r = 0; r < R_DIM; ++r) {
                    const float4 u4 = *reinterpret_cast<const float4*>(u_lds + r * QD + dl);
                    #pragma unroll
                    for (int k = 0; k < RB; ++k) pp[k][r] += dot4(v4[k], u4);
                }
            }
            __syncthreads();   // all waves done with this quarter before restage
        }

        // butterfly reduce across the 64-lane wave
        #pragma unroll
        for (int s = 32; s >= 1; s >>= 1) {
            #pragma unroll
            for (int k = 0; k < RB; ++k) {
                xv[k] += __shfl_xor(xv[k], s, 64);
                #pragma unroll
                for (int r = 0; r < R_DIM; ++r) pp[k][r] += __shfl_xor(pp[k][r], s, 64);
            }
        }
        if (lane == 0) {
            #pragma unroll
            for (int k = 0; k < RB; ++k) {
                const int rl = rl0 + k;
                if (row0 + rl < nrows) {
                    #pragma unroll
                    for (int r = 0; r < R_DIM; ++r)
                        sq_lds[rl * R_DIM + r] = pp[k][r] * pp[k][r];
                    fac_lds[rl] = 1.0f + 1.0f / (1.0f + __expf(-xv[k]));
                }
            }
        }
    }
    __syncthreads();

    // ---- phase 2: two d-passes; thread owns d = p*1024 + 2*tid, +1 ----
    #pragma unroll
    for (int p = 0; p < 2; ++p) {
        const int dd = p * (2 * THREADS) + tid * 2;
        float w0[R_DIM], w1[R_DIM];
        const float4* p0 = reinterpret_cast<const float4*>(W + (size_t)dd * R_DIM);
        const float4* p1 = reinterpret_cast<const float4*>(W + (size_t)(dd + 1) * R_DIM);
        #pragma unroll
        for (int c = 0; c < 4; ++c) {
            *reinterpret_cast<float4*>(&w0[c * 4]) = p0[c];
            *reinterpret_cast<float4*>(&w1[c * 4]) = p1[c];
        }

        for (int rl = 0; rl < ROWS; ++rl) {
            if (row0 + rl >= nrows) break;
            float sqv[R_DIM];
            #pragma unroll
            for (int c = 0; c < 4; ++c)
                *reinterpret_cast<float4*>(&sqv[c * 4]) =
                    *reinterpret_cast<const float4*>(sq_lds + rl * R_DIM + c * 4);
            const float fac = fac_lds[rl];
            float o0 = 0.0f, o1 = 0.0f;
            #pragma unroll
            for (int r = 0; r < R_DIM; ++r) {
                o0 += sqv[r] * w0[r];
                o1 += sqv[r] * w1[r];
            }
            f32x2 o;
            o.x = clamp5(o0 * fac);
            o.y = clamp5(o1 * fac);
            __builtin_nontemporal_store(o,
                reinterpret_cast<f32x2*>(out + (size_t)(row0 + rl) * D_DIM + dd));
        }
    }
}

extern "C" void kernel_launch(void* const* d_in, const int* in_sizes, int n_in,
                              void* d_out, int out_size, void* d_ws, size_t ws_size,
                              hipStream_t stream) {
    const float* v  = (const float*)d_in[0];
    const float* x  = (const float*)d_in[1];
    const float* U  = (const float*)d_in[2];
    const float* W  = (const float*)d_in[3];
    const float* Vw = (const float*)d_in[4];
    float* out = (float*)d_out;

    const int nrows = in_sizes[0] / D_DIM;        // B*S = 16384
    const int grid  = (nrows + ROWS - 1) / ROWS;  // 1024 -> exactly 4 WGs/CU

    lrc_kernel<<<grid, THREADS, 0, stream>>>(v, x, U, W, Vw, out, nrows);
}

// Round 7
// 124.552 us; speedup vs baseline: 7.5608x; 7.5608x over previous
//
#include <hip/hip_runtime.h>
#include <math.h>

// LowRankChristoffel: out = clip((((v@U)^2) @ W^T) * (1+sigmoid(x@Vw^T)), +-5)
// B=4, S=4096, D=2048, R=16, fp32.
//
// R7 = R6 structure WITHOUT the amdgpu_waves_per_eu pin (R6's VGPR=32 spill
// disaster: WRITE 2.1 GB of scratch). R4/R5 proved this RB=2 body naturally
// compiles to 64 VGPR with zero spill, which is exactly the 8-waves/EU budget.
//  - 512-thread WGs, U^T staged in 32 KiB quarters -> ~34 KiB LDS/WG
//    -> 4 WG/CU = 32 waves/CU (2x R4's occupancy).
//  - stage->sync->accumulate->sync x4, pp[2][16] live across quarters.
//  - phase 2: W in registers, 2 d-passes, nontemporal f32x2 stores.

constexpr int D_DIM   = 2048;
constexpr int R_DIM   = 16;
constexpr int ROWS    = 16;      // rows per block
constexpr int THREADS = 512;     // 8 waves
constexpr int WAVES   = THREADS / 64;
constexpr int RB      = 2;       // rows per wave
constexpr int QD      = 512;     // d-columns per staged quarter
constexpr int NQ      = D_DIM / QD;   // 4 quarters

typedef float f32x2 __attribute__((ext_vector_type(2)));

__device__ __forceinline__ float clamp5(float v) {
    return fminf(fmaxf(v, -5.0f), 5.0f);
}
__device__ __forceinline__ float dot4(float4 a, float4 b) {
    return a.x * b.x + a.y * b.y + a.z * b.z + a.w * b.w;
}

extern "C" __global__ void __launch_bounds__(THREADS)
lrc_kernel(const float* __restrict__ v, const float* __restrict__ x,
           const float* __restrict__ U, const float* __restrict__ W,
           const float* __restrict__ Vw, float* __restrict__ out, int nrows)
{
    __shared__ float u_lds[R_DIM * QD];      // 32 KiB, one quarter of U^T
    __shared__ float sq_lds[ROWS * R_DIM];   // 1 KiB
    __shared__ float fac_lds[ROWS];

    const int tid  = threadIdx.x;
    const int lane = tid & 63;
    const int wave = tid >> 6;          // 0..7
    const int row0 = blockIdx.x * ROWS;

    // ---- phase 1: quarter-staged U^T; pp accumulators live across quarters ----
    {
        const int rl0 = wave * RB;
        const float* vb = v + (size_t)(row0 + rl0) * D_DIM;
        const float* xb = x + (size_t)(row0 + rl0) * D_DIM;

        float pp[RB][R_DIM];
        float xv[RB];
        #pragma unroll
        for (int k = 0; k < RB; ++k) {
            xv[k] = 0.0f;
            #pragma unroll
            for (int r = 0; r < R_DIM; ++r) pp[k][r] = 0.0f;
        }

        for (int q = 0; q < NQ; ++q) {
            // stage quarter q transposed: thread owns d = q*QD + tid
            {
                const int d = q * QD + tid;
                const float4* p = reinterpret_cast<const float4*>(U + (size_t)d * R_DIM);
                float u[R_DIM];
                #pragma unroll
                for (int c = 0; c < 4; ++c)
                    *reinterpret_cast<float4*>(&u[c * 4]) = p[c];
                #pragma unroll
                for (int r = 0; r < R_DIM; ++r)
                    u_lds[r * QD + tid] = u[r];   // stride-1 across threads: conflict-free
            }
            __syncthreads();

            #pragma unroll
            for (int i = 0; i < QD / 256; ++i) {       // 2 iters per quarter
                const int dl = i * 256 + lane * 4;     // local d in quarter
                const int dg = q * QD + dl;            // global d
                float4 v4[RB], x4[RB];
                #pragma unroll
                for (int k = 0; k < RB; ++k) {
                    v4[k] = *reinterpret_cast<const float4*>(vb + (size_t)k * D_DIM + dg);
                    x4[k] = *reinterpret_cast<const float4*>(xb + (size_t)k * D_DIM + dg);
                }
                const float4 vw4 = *reinterpret_cast<const float4*>(Vw + dg);  // L1/L2 hit
                #pragma unroll
                for (int k = 0; k < RB; ++k) xv[k] += dot4(x4[k], vw4);
                #pragma unroll
                for (int r = 0; r < R_DIM; ++r) {
                    const float4 u4 = *reinterpret_cast<const float4*>(u_lds + r * QD + dl);
                    #pragma unroll
                    for (int k = 0; k < RB; ++k) pp[k][r] += dot4(v4[k], u4);
                }
            }
            __syncthreads();   // all waves done with this quarter before restage
        }

        // butterfly reduce across the 64-lane wave
        #pragma unroll
        for (int s = 32; s >= 1; s >>= 1) {
            #pragma unroll
            for (int k = 0; k < RB; ++k) {
                xv[k] += __shfl_xor(xv[k], s, 64);
                #pragma unroll
                for (int r = 0; r < R_DIM; ++r) pp[k][r] += __shfl_xor(pp[k][r], s, 64);
            }
        }
        if (lane == 0) {
            #pragma unroll
            for (int k = 0; k < RB; ++k) {
                const int rl = rl0 + k;
                if (row0 + rl < nrows) {
                    #pragma unroll
                    for (int r = 0; r < R_DIM; ++r)
                        sq_lds[rl * R_DIM + r] = pp[k][r] * pp[k][r];
                    fac_lds[rl] = 1.0f + 1.0f / (1.0f + __expf(-xv[k]));
                }
            }
        }
    }
    __syncthreads();

    // ---- phase 2: two d-passes; thread owns d = p*1024 + 2*tid, +1 ----
    #pragma unroll
    for (int p = 0; p < 2; ++p) {
        const int dd = p * (2 * THREADS) + tid * 2;
        float w0[R_DIM], w1[R_DIM];
        const float4* p0 = reinterpret_cast<const float4*>(W + (size_t)dd * R_DIM);
        const float4* p1 = reinterpret_cast<const float4*>(W + (size_t)(dd + 1) * R_DIM);
        #pragma unroll
        for (int c = 0; c < 4; ++c) {
            *reinterpret_cast<float4*>(&w0[c * 4]) = p0[c];
            *reinterpret_cast<float4*>(&w1[c * 4]) = p1[c];
        }

        for (int rl = 0; rl < ROWS; ++rl) {
            if (row0 + rl >= nrows) break;
            float sqv[R_DIM];
            #pragma unroll
            for (int c = 0; c < 4; ++c)
                *reinterpret_cast<float4*>(&sqv[c * 4]) =
                    *reinterpret_cast<const float4*>(sq_lds + rl * R_DIM + c * 4);
            const float fac = fac_lds[rl];
            float o0 = 0.0f, o1 = 0.0f;
            #pragma unroll
            for (int r = 0; r < R_DIM; ++r) {
                o0 += sqv[r] * w0[r];
                o1 += sqv[r] * w1[r];
            }
            f32x2 o;
            o.x = clamp5(o0 * fac);
            o.y = clamp5(o1 * fac);
            __builtin_nontemporal_store(o,
                reinterpret_cast<f32x2*>(out + (size_t)(row0 + rl) * D_DIM + dd));
        }
    }
}

extern "C" void kernel_launch(void* const* d_in, const int* in_sizes, int n_in,
                              void* d_out, int out_size, void* d_ws, size_t ws_size,
                              hipStream_t stream) {
    const float* v  = (const float*)d_in[0];
    const float* x  = (const float*)d_in[1];
    const float* U  = (const float*)d_in[2];
    const float* W  = (const float*)d_in[3];
    const float* Vw = (const float*)d_in[4];
    float* out = (float*)d_out;

    const int nrows = in_sizes[0] / D_DIM;        // B*S = 16384
    const int grid  = (nrows + ROWS - 1) / ROWS;  // 1024 -> 4 WGs/CU

    lrc_kernel<<<grid, THREADS, 0, stream>>>(v, x, U, W, Vw, out, nrows);
}

// Round 8
// 106.548 us; speedup vs baseline: 8.8384x; 1.1690x over previous
//
#include <hip/hip_runtime.h>
#include <math.h>

// LowRankChristoffel: out = clip((((v@U)^2) @ W^T) * (1+sigmoid(x@Vw^T)), +-5)
// B=4, S=4096, D=2048, R=16, fp32. HBM floor ~265 MB -> ~42 us.
//
// R8 = R4's proven shell (stage U^T once, 1 persistent WG/CU, 256 WGs) with
// its three stall structures removed:
//  1) RB=4 single batch (pin waves_per_eu(4,4) -> 128 VGPR budget; LDS already
//     caps at 4 waves/EU so the pin costs nothing): u4 LDS reads amortized
//     over 4 rows, 8 HBM loads in flight per wave-iter.
//  2) no second barrier / no sq_lds: butterfly leaves full sums in ALL lanes;
//     same wave squares, sigmoids, and writes its own 4 rows -> waves de-sync.
//  3) phase 2 reads W^T from L2 (transposed once into d_ws by prologue),
//     coalesced 1KB/wave, reused across 4 rows.

constexpr int D_DIM   = 2048;
constexpr int R_DIM   = 16;
constexpr int ROWS    = 64;      // rows per block
constexpr int THREADS = 1024;    // 16 waves
constexpr int RB      = 4;       // rows per wave, single batch

typedef float f32x4 __attribute__((ext_vector_type(4)));

// LDS: U^T [16][2048] + Vw [2048]  = 136 KiB
constexpr int SMEM_FLOATS = R_DIM * D_DIM + D_DIM;
constexpr size_t SMEM_BYTES = (size_t)SMEM_FLOATS * sizeof(float);

__device__ __forceinline__ float clamp5(float v) {
    return fminf(fmaxf(v, -5.0f), 5.0f);
}
__device__ __forceinline__ float dot4(float4 a, float4 b) {
    return a.x * b.x + a.y * b.y + a.z * b.z + a.w * b.w;
}

// ---- prologue: W [2048][16] -> Wt [16][2048] in d_ws (proven in R5) ----
extern "C" __global__ void transpose_w(const float* __restrict__ W,
                                       float* __restrict__ Wt) {
    const int o = blockIdx.x * blockDim.x + threadIdx.x;
    if (o < R_DIM * D_DIM) {
        const int r = o >> 11;          // / 2048
        const int d = o & (D_DIM - 1);  // % 2048
        Wt[o] = W[(d << 4) + r];
    }
}

extern "C" __global__ void __launch_bounds__(THREADS)
__attribute__((amdgpu_waves_per_eu(4, 4)))
lrc_kernel(const float* __restrict__ v, const float* __restrict__ x,
           const float* __restrict__ U, const float* __restrict__ Wt,
           const float* __restrict__ Vw, float* __restrict__ out, int nrows)
{
    extern __shared__ float smem[];
    float* u_lds  = smem;                    // [R_DIM][D_DIM]
    float* vw_lds = u_lds + R_DIM * D_DIM;   // [D_DIM]

    const int tid  = threadIdx.x;
    const int lane = tid & 63;
    const int wave = tid >> 6;          // 0..15
    const int row0 = blockIdx.x * ROWS;

    // ---- stage Vw ----
    for (int i = tid; i < D_DIM / 4; i += THREADS)
        reinterpret_cast<float4*>(vw_lds)[i] = reinterpret_cast<const float4*>(Vw)[i];

    // ---- stage U transposed: thread owns d = 2*tid, 2*tid+1 ----
    {
        const int dd = tid * 2;
        float u0[R_DIM], u1[R_DIM];
        const float4* p0 = reinterpret_cast<const float4*>(U + (size_t)dd * R_DIM);
        const float4* p1 = reinterpret_cast<const float4*>(U + (size_t)(dd + 1) * R_DIM);
        #pragma unroll
        for (int c = 0; c < 4; ++c) {
            *reinterpret_cast<float4*>(&u0[c * 4]) = p0[c];
            *reinterpret_cast<float4*>(&u1[c * 4]) = p1[c];
        }
        #pragma unroll
        for (int r = 0; r < R_DIM; ++r)
            *reinterpret_cast<float2*>(&u_lds[r * D_DIM + dd]) = make_float2(u0[r], u1[r]);
    }
    __syncthreads();   // the ONLY barrier

    // ---- phase 1: wave owns rows rl0..rl0+3; single batch, RB=4 ----
    const int rl0 = wave * RB;
    const float* vb = v + (size_t)(row0 + rl0) * D_DIM;
    const float* xb = x + (size_t)(row0 + rl0) * D_DIM;

    float pp[RB][R_DIM];
    float xv[RB];
    #pragma unroll
    for (int k = 0; k < RB; ++k) {
        xv[k] = 0.0f;
        #pragma unroll
        for (int r = 0; r < R_DIM; ++r) pp[k][r] = 0.0f;
    }

    for (int i = 0; i < D_DIM / 256; ++i) {    // 8 iters
        const int d0 = i * 256 + lane * 4;
        float4 v4[RB], x4[RB];
        #pragma unroll
        for (int k = 0; k < RB; ++k) {
            v4[k] = *reinterpret_cast<const float4*>(vb + (size_t)k * D_DIM + d0);
            x4[k] = *reinterpret_cast<const float4*>(xb + (size_t)k * D_DIM + d0);
        }
        const float4 vw4 = *reinterpret_cast<const float4*>(vw_lds + d0);
        #pragma unroll
        for (int k = 0; k < RB; ++k) xv[k] += dot4(x4[k], vw4);
        #pragma unroll
        for (int r = 0; r < R_DIM; ++r) {
            const float4 u4 = *reinterpret_cast<const float4*>(u_lds + r * D_DIM + d0);
            #pragma unroll
            for (int k = 0; k < RB; ++k) pp[k][r] += dot4(v4[k], u4);
        }
    }

    // ---- butterfly reduce; ALL lanes end with full sums ----
    #pragma unroll
    for (int s = 32; s >= 1; s >>= 1) {
        #pragma unroll
        for (int k = 0; k < RB; ++k) {
            xv[k] += __shfl_xor(xv[k], s, 64);
            #pragma unroll
            for (int r = 0; r < R_DIM; ++r) pp[k][r] += __shfl_xor(pp[k][r], s, 64);
        }
    }

    // square + modulation, in registers (every lane, redundant but cheap)
    float fac[RB];
    #pragma unroll
    for (int k = 0; k < RB; ++k) {
        fac[k] = 1.0f + 1.0f / (1.0f + __expf(-xv[k]));
        #pragma unroll
        for (int r = 0; r < R_DIM; ++r) pp[k][r] = pp[k][r] * pp[k][r];
    }

    // ---- phase 2 (no barrier): wave writes its own 4 rows; Wt from L2 ----
    if (row0 + rl0 + RB <= nrows) {
        float* ob = out + (size_t)(row0 + rl0) * D_DIM;
        for (int i = 0; i < D_DIM / 256; ++i) {
            const int d0 = i * 256 + lane * 4;
            float4 wt4[R_DIM];
            #pragma unroll
            for (int r = 0; r < R_DIM; ++r)
                wt4[r] = *reinterpret_cast<const float4*>(Wt + r * D_DIM + d0);  // L2-hit, coalesced
            #pragma unroll
            for (int k = 0; k < RB; ++k) {
                float4 o = make_float4(0.f, 0.f, 0.f, 0.f);
                #pragma unroll
                for (int r = 0; r < R_DIM; ++r) {
                    o.x += pp[k][r] * wt4[r].x;
                    o.y += pp[k][r] * wt4[r].y;
                    o.z += pp[k][r] * wt4[r].z;
                    o.w += pp[k][r] * wt4[r].w;
                }
                f32x4 ov;
                ov.x = clamp5(o.x * fac[k]);
                ov.y = clamp5(o.y * fac[k]);
                ov.z = clamp5(o.z * fac[k]);
                ov.w = clamp5(o.w * fac[k]);
                __builtin_nontemporal_store(ov,
                    reinterpret_cast<f32x4*>(ob + (size_t)k * D_DIM + d0));
            }
        }
    }
}

extern "C" void kernel_launch(void* const* d_in, const int* in_sizes, int n_in,
                              void* d_out, int out_size, void* d_ws, size_t ws_size,
                              hipStream_t stream) {
    const float* v  = (const float*)d_in[0];
    const float* x  = (const float*)d_in[1];
    const float* U  = (const float*)d_in[2];
    const float* W  = (const float*)d_in[3];
    const float* Vw = (const float*)d_in[4];
    float* out = (float*)d_out;
    float* Wt  = (float*)d_ws;                    // 128 KiB scratch

    const int nrows = in_sizes[0] / D_DIM;        // B*S = 16384
    const int grid  = (nrows + ROWS - 1) / ROWS;  // 256 -> 1 persistent WG/CU

    transpose_w<<<(R_DIM * D_DIM + 255) / 256, 256, 0, stream>>>(W, Wt);

    (void)hipFuncSetAttribute((const void*)lrc_kernel,
                              hipFuncAttributeMaxDynamicSharedMemorySize,
                              (int)SMEM_BYTES);
    lrc_kernel<<<grid, THREADS, SMEM_BYTES, stream>>>(v, x, U, Wt, Vw, out, nrows);
}